// Round 10
// baseline (1007.942 us; speedup 1.0000x reference)
//
#include <hip/hip_runtime.h>
#include <stdint.h>

#define N_ROWS 12288
#define GSZ (128 * 12288)  // elements per G matrix (bf16)
#define NPART_OFF (9437184 / 4)          // float offset of node partials in ws
#define EPART_OFF ((9437184 + 6291456) / 4)

typedef __attribute__((ext_vector_type(8))) short bf16x8;
typedef __attribute__((ext_vector_type(4))) float f32x4;

__device__ __forceinline__ uint32_t f2bf(float x) {
  union { float f; uint32_t u; } c; c.f = x;
  return (c.u + 0x7FFFu + ((c.u >> 16) & 1u)) >> 16;
}
__device__ __forceinline__ uint32_t pk_bf(float a, float b) {
  return f2bf(a) | (f2bf(b) << 16);
}
__device__ __forceinline__ uint32_t pk_pos(float a, float b) {
  return (a > 0.f ? 0x3F80u : 0u) | (b > 0.f ? 0x3F800000u : 0u);
}
__device__ __forceinline__ uint32_t pk_neg(float a, float b) {
  return (a < 0.f ? 0x3F80u : 0u) | (b < 0.f ? 0x3F800000u : 0u);
}

// ---------------------------------------------------------------------------
// Kernel 1: G_j = feats @ W_j  (fp32), stored bf16 TRANSPOSED:
//   gt[j][n][k] = (feats @ W_j)[k][n]
// ---------------------------------------------------------------------------
__global__ __launch_bounds__(256) void gw_kernel(
    const float* __restrict__ feats, const float* __restrict__ node_w,
    const float* __restrict__ edge_w, uint16_t* __restrict__ gt) {
  __shared__ float lf[16 * 128];
  const int t = threadIdx.x;
  const int kb = blockIdx.x * 16;
  {
    const float4* src = (const float4*)(feats + (size_t)kb * 128);
    float4* dst = (float4*)lf;
    dst[t] = src[t];
    dst[t + 256] = src[t + 256];
  }
  __syncthreads();
  const int n = t & 127;
  const int rh = t >> 7;
  const float* wb[3] = {node_w, node_w + 128 * 128, edge_w};
#pragma unroll
  for (int j = 0; j < 3; ++j) {
    const float* W = wb[j] + n;
    float acc[8];
#pragma unroll
    for (int q = 0; q < 8; ++q) acc[q] = 0.f;
    for (int i = 0; i < 128; i += 4) {
      const float w0 = W[(i + 0) * 128];
      const float w1 = W[(i + 1) * 128];
      const float w2 = W[(i + 2) * 128];
      const float w3 = W[(i + 3) * 128];
#pragma unroll
      for (int q = 0; q < 8; ++q) {
        const float4 f = *(const float4*)&lf[(rh * 8 + q) * 128 + i];
        acc[q] = fmaf(f.w, w3, fmaf(f.z, w2, fmaf(f.y, w1, fmaf(f.x, w0, acc[q]))));
      }
    }
    uint4 o;
    o.x = pk_bf(acc[0], acc[1]);
    o.y = pk_bf(acc[2], acc[3]);
    o.z = pk_bf(acc[4], acc[5]);
    o.w = pk_bf(acc[6], acc[7]);
    *(uint4*)(gt + (size_t)j * GSZ + (size_t)n * N_ROWS + kb + rh * 8) = o;
  }
}

// ---------------------------------------------------------------------------
// Kernel 2: K-sliced partials. 1536 blocks x 256 thr (4 waves), now SIX
// blocks/CU resident (LDS 24KB x 6 = 144KB <= 160; VGPR 64 x 24 waves =
// 1536 <= 2048) -> the whole 1536-block grid is co-resident in ONE clean
// round, zero ragged tail, 1.5x more independent HBM streams per CU.
// BM=64, BK=32, 8 K-slices of 1536 (48 iters). slice = bid&7 = XCD id.
// Per-iter structure identical to the R6 best: pack+ds_write, __syncthreads,
// prefetch kt+1, B-loads+MFMA (compiler-scheduled).
// LDS tile: 3 mats x 64 rows x 32 bf16 (64B rows); granule swizzle
// g ^= (row>>2)&3.
// ---------------------------------------------------------------------------
__global__ __launch_bounds__(256, 6) void fgc_main(
    const float* __restrict__ node_adj, const float* __restrict__ edge_adj,
    const uint16_t* __restrict__ gt, float* __restrict__ node_part,
    float* __restrict__ edge_part) {
  __shared__ __align__(128) char smem[24576];  // 2 x (pos|neg|edge) x 64x32 bf16
  const int t = threadIdx.x;
  const int l = t & 63;
  const int w = t >> 6;
  const int bid = blockIdx.x;
  const int slice = bid & 7;
  const int row0 = (bid >> 3) * 64;
  const size_t k0 = (size_t)slice * 1536;

  // staging: thread t owns (row t>>2, granule t&3) = 8 consecutive f32
  const int r = t >> 2, o = t & 3;
  const float* np_ = node_adj + (size_t)(row0 + r) * N_ROWS + k0 + o * 8;
  const float* ep_ = edge_adj + (size_t)(row0 + r) * N_ROWS + k0 + o * 8;
  const int wOff = r * 64 + ((o ^ ((r >> 2) & 3)) * 16);  // swizzled byte offs

  // A-frag read: row = mf*16 + r15, granule gq, swizzle by (row>>2)&3
  const int r15 = l & 15;
  const int gq = l >> 4;
  const int abase = r15 * 64 + ((gq ^ ((r15 >> 2) & 3)) * 16);

  // B lane base: n = w*32 + nf*16 + r15, k = k0 + kt*32 + gq*8
  const uint16_t* gB = gt + (size_t)(w * 32 + r15) * N_ROWS + k0 + gq * 8;

  f32x4 accn[4][2], acce[4][2];
#pragma unroll
  for (int a = 0; a < 4; ++a)
#pragma unroll
    for (int b = 0; b < 2; ++b) {
      accn[a][b] = {0.f, 0.f, 0.f, 0.f};
      acce[a][b] = {0.f, 0.f, 0.f, 0.f};
    }

  float4 rn0, rn1, re0, re1;
  rn0 = *(const float4*)(np_);
  rn1 = *(const float4*)(np_ + 4);
  re0 = *(const float4*)(ep_);
  re1 = *(const float4*)(ep_ + 4);

  for (int kt = 0; kt < 48; ++kt) {
    char* wb2 = smem + (kt & 1) * 12288;
    {
      uint4 P, Q, E;
      P.x = pk_pos(rn0.x, rn0.y); P.y = pk_pos(rn0.z, rn0.w);
      P.z = pk_pos(rn1.x, rn1.y); P.w = pk_pos(rn1.z, rn1.w);
      Q.x = pk_neg(rn0.x, rn0.y); Q.y = pk_neg(rn0.z, rn0.w);
      Q.z = pk_neg(rn1.x, rn1.y); Q.w = pk_neg(rn1.z, rn1.w);
      E.x = pk_bf(re0.x, re0.y);  E.y = pk_bf(re0.z, re0.w);
      E.z = pk_bf(re1.x, re1.y);  E.w = pk_bf(re1.z, re1.w);
      *(uint4*)(wb2 + wOff) = P;
      *(uint4*)(wb2 + 4096 + wOff) = Q;
      *(uint4*)(wb2 + 8192 + wOff) = E;
    }
    __syncthreads();
    // prefetch next tile AFTER the barrier: the barrier's vmcnt drain then
    // only covers already-consumed loads.
    if (kt < 47) {
      const size_t ko = (size_t)(kt + 1) * 32;
      rn0 = *(const float4*)(np_ + ko);
      rn1 = *(const float4*)(np_ + ko + 4);
      re0 = *(const float4*)(ep_ + ko);
      re1 = *(const float4*)(ep_ + ko + 4);
    }
    const char* rb = smem + (kt & 1) * 12288;
    bf16x8 ap[4], an[4], ae[4];
#pragma unroll
    for (int mf = 0; mf < 4; ++mf) {
      ap[mf] = *(const bf16x8*)(rb + abase + mf * 1024);
      an[mf] = *(const bf16x8*)(rb + 4096 + abase + mf * 1024);
      ae[mf] = *(const bf16x8*)(rb + 8192 + abase + mf * 1024);
    }
    const uint16_t* gk = gB + kt * 32;
#pragma unroll
    for (int nf = 0; nf < 2; ++nf) {
      const uint16_t* gp = gk + (size_t)nf * 16 * N_ROWS;
      const bf16x8 b1 = *(const bf16x8*)(gp);
      const bf16x8 b2 = *(const bf16x8*)(gp + GSZ);
      const bf16x8 b3 = *(const bf16x8*)(gp + 2 * GSZ);
#pragma unroll
      for (int mf = 0; mf < 4; ++mf)
        accn[mf][nf] = __builtin_amdgcn_mfma_f32_16x16x32_bf16(ap[mf], b1, accn[mf][nf], 0, 0, 0);
#pragma unroll
      for (int mf = 0; mf < 4; ++mf)
        accn[mf][nf] = __builtin_amdgcn_mfma_f32_16x16x32_bf16(an[mf], b2, accn[mf][nf], 0, 0, 0);
#pragma unroll
      for (int mf = 0; mf < 4; ++mf)
        acce[mf][nf] = __builtin_amdgcn_mfma_f32_16x16x32_bf16(ae[mf], b3, acce[mf][nf], 0, 0, 0);
    }
  }

  // accumulate partials: C/D frag row=(lane>>4)*4+q, col=lane&15
#pragma unroll
  for (int nf = 0; nf < 2; ++nf) {
    const int col = w * 32 + nf * 16 + r15;
#pragma unroll
    for (int mf = 0; mf < 4; ++mf) {
      const f32x4 nv = accn[mf][nf];
      const f32x4 ev = acce[mf][nf];
#pragma unroll
      for (int q = 0; q < 4; ++q) {
        const size_t idx = (size_t)(row0 + mf * 16 + gq * 4 + q) * 128 + col;
        unsafeAtomicAdd(&node_part[idx], nv[q]);
        unsafeAtomicAdd(&edge_part[idx], ev[q]);
      }
    }
  }
}

// ---------------------------------------------------------------------------
// Kernel 3: out = relu(node_part + node_bias) + edge_part + edge_bias
// ---------------------------------------------------------------------------
__global__ __launch_bounds__(256) void fgc_final(
    const float* __restrict__ node_part, const float* __restrict__ edge_part,
    const float* __restrict__ node_bias, const float* __restrict__ edge_bias,
    float* __restrict__ out) {
  const int idx = blockIdx.x * 256 + threadIdx.x;  // one float4 each
  const int col = (idx * 4) & 127;
  const float4 n = ((const float4*)node_part)[idx];
  const float4 e = ((const float4*)edge_part)[idx];
  const float4 nb = *(const float4*)(node_bias + col);
  const float4 eb = *(const float4*)(edge_bias + col);
  float4 o;
  o.x = fmaxf(n.x + nb.x, 0.f) + e.x + eb.x;
  o.y = fmaxf(n.y + nb.y, 0.f) + e.y + eb.y;
  o.z = fmaxf(n.z + nb.z, 0.f) + e.z + eb.z;
  o.w = fmaxf(n.w + nb.w, 0.f) + e.w + eb.w;
  ((float4*)out)[idx] = o;
}

extern "C" void kernel_launch(void* const* d_in, const int* in_sizes, int n_in,
                              void* d_out, int out_size, void* d_ws, size_t ws_size,
                              hipStream_t stream) {
  const float* feats = (const float*)d_in[0];
  const float* node_adj = (const float*)d_in[1];
  const float* edge_adj = (const float*)d_in[2];
  const float* node_w = (const float*)d_in[3];
  const float* node_b = (const float*)d_in[4];
  const float* edge_w = (const float*)d_in[5];
  const float* edge_b = (const float*)d_in[6];
  uint16_t* gt = (uint16_t*)d_ws;                 // 9.44 MB
  float* node_part = (float*)d_ws + NPART_OFF;    // 6.29 MB
  float* edge_part = (float*)d_ws + EPART_OFF;    // 6.29 MB

  gw_kernel<<<768, 256, 0, stream>>>(feats, node_w, edge_w, gt);
  hipMemsetAsync((char*)d_ws + 9437184, 0, 2 * 6291456, stream);
  fgc_main<<<1536, 256, 0, stream>>>(node_adj, edge_adj, gt,
                                     node_part, edge_part);
  fgc_final<<<1536, 256, 0, stream>>>(node_part, edge_part, node_b, edge_b,
                                      (float*)d_out);
}

// Round 11
// 352.843 us; speedup vs baseline: 2.8566x; 2.8566x over previous
//
#include <hip/hip_runtime.h>
#include <stdint.h>

#define N_ROWS 12288
#define GSZ (128 * 12288)  // elements per G matrix (bf16)
#define NPART_OFF (9437184 / 4)          // float offset of node partials in ws
#define EPART_OFF ((9437184 + 6291456) / 4)

typedef __attribute__((ext_vector_type(8))) short bf16x8;
typedef __attribute__((ext_vector_type(4))) float f32x4;

__device__ __forceinline__ uint32_t f2bf(float x) {
  union { float f; uint32_t u; } c; c.f = x;
  return (c.u + 0x7FFFu + ((c.u >> 16) & 1u)) >> 16;
}
__device__ __forceinline__ uint32_t pk_bf(float a, float b) {
  return f2bf(a) | (f2bf(b) << 16);
}
__device__ __forceinline__ uint32_t pk_pos(float a, float b) {
  return (a > 0.f ? 0x3F80u : 0u) | (b > 0.f ? 0x3F800000u : 0u);
}
__device__ __forceinline__ uint32_t pk_neg(float a, float b) {
  return (a < 0.f ? 0x3F80u : 0u) | (b < 0.f ? 0x3F800000u : 0u);
}

#define MFMA __builtin_amdgcn_mfma_f32_16x16x32_bf16

// ---------------------------------------------------------------------------
// Kernel 1: G_j = feats @ W_j  (fp32), stored bf16 TRANSPOSED:
//   gt[j][n][k] = (feats @ W_j)[k][n]
// ---------------------------------------------------------------------------
__global__ __launch_bounds__(256) void gw_kernel(
    const float* __restrict__ feats, const float* __restrict__ node_w,
    const float* __restrict__ edge_w, uint16_t* __restrict__ gt) {
  __shared__ float lf[16 * 128];
  const int t = threadIdx.x;
  const int kb = blockIdx.x * 16;
  {
    const float4* src = (const float4*)(feats + (size_t)kb * 128);
    float4* dst = (float4*)lf;
    dst[t] = src[t];
    dst[t + 256] = src[t + 256];
  }
  __syncthreads();
  const int n = t & 127;
  const int rh = t >> 7;
  const float* wb[3] = {node_w, node_w + 128 * 128, edge_w};
#pragma unroll
  for (int j = 0; j < 3; ++j) {
    const float* W = wb[j] + n;
    float acc[8];
#pragma unroll
    for (int q = 0; q < 8; ++q) acc[q] = 0.f;
    for (int i = 0; i < 128; i += 4) {
      const float w0 = W[(i + 0) * 128];
      const float w1 = W[(i + 1) * 128];
      const float w2 = W[(i + 2) * 128];
      const float w3 = W[(i + 3) * 128];
#pragma unroll
      for (int q = 0; q < 8; ++q) {
        const float4 f = *(const float4*)&lf[(rh * 8 + q) * 128 + i];
        acc[q] = fmaf(f.w, w3, fmaf(f.z, w2, fmaf(f.y, w1, fmaf(f.x, w0, acc[q]))));
      }
    }
    uint4 o;
    o.x = pk_bf(acc[0], acc[1]);
    o.y = pk_bf(acc[2], acc[3]);
    o.z = pk_bf(acc[4], acc[5]);
    o.w = pk_bf(acc[6], acc[7]);
    *(uint4*)(gt + (size_t)j * GSZ + (size_t)n * N_ROWS + kb + rh * 8) = o;
  }
}

// ---------------------------------------------------------------------------
// Kernel 2: split node/edge block types to halve B (gt) traffic per CU.
// 1536 blocks x 512 thr (8 waves). bid<768: NODE (pos+neg planes, 2 B-loads,
// accn[8]); bid>=768: EDGE (1 plane, 1 B-load, acce[8]). BM=128, BK=32,
// 8 K-slices of 1536 (48 iters), slice = b&7 = XCD (gt slice L2-resident).
// Each wave owns 16 cols (nf=1, mf=8) -> B bytes/block-iter = 16KB(node)/
// 8KB(edge) vs 16KB adjacency: B total 1.77GB -> 0.88GB (the per-CU
// vector-memory pipe was the measured ~13 B/cyc ceiling; B was 60%).
// LDS: 2 bufs x 2 planes x 128 rows x 32 bf16 (64B rows) = 32KB max.
// Granule swizzle g ^ ((row>>1)&3): exact 2-way (free) on write and read.
// Per-iter structure = proven R6: pack+ds_write, __syncthreads, prefetch,
// B-loads + MFMA. VGPR capped 128 via __launch_bounds__(512,4); acc=32.
// ---------------------------------------------------------------------------
__global__ __launch_bounds__(512, 4) void fgc_main(
    const float* __restrict__ node_adj, const float* __restrict__ edge_adj,
    const uint16_t* __restrict__ gt, float* __restrict__ node_part,
    float* __restrict__ edge_part) {
  __shared__ __align__(128) char smem[32768];
  const int t = threadIdx.x;
  const int l = t & 63;
  const int w = t >> 6;  // 0..7: n-slice
  const bool isNode = (blockIdx.x < 768);
  const int b = isNode ? blockIdx.x : blockIdx.x - 768;
  const int slice = b & 7;
  const int row0 = (b >> 3) * 128;   // 96 row-tiles
  const size_t k0 = (size_t)slice * 1536;

  // staging: thread t owns (row t>>2, granule t&3) = 8 consecutive f32
  const int r = t >> 2, o = t & 3;
  const float* src = (isNode ? node_adj : edge_adj) +
                     (size_t)(row0 + r) * N_ROWS + k0 + o * 8;
  const int wOff = r * 64 + ((o ^ ((r >> 1) & 3)) * 16);

  // A-frag read: row = mf*16 + r15, granule gq, swizzle (row>>1)&3
  const int r15 = l & 15;
  const int gq = l >> 4;

  // B lane base: n = w*16 + r15, k = k0 + kt*32 + gq*8
  const uint16_t* gB = gt + (size_t)(w * 16 + r15) * N_ROWS + k0 + gq * 8;

  f32x4 acc[8];
#pragma unroll
  for (int a = 0; a < 8; ++a) acc[a] = {0.f, 0.f, 0.f, 0.f};

  float4 rn0, rn1;
  rn0 = *(const float4*)(src);
  rn1 = *(const float4*)(src + 4);

  if (isNode) {
    for (int kt = 0; kt < 48; ++kt) {
      char* wb2 = smem + (kt & 1) * 16384;
      {
        uint4 P, Q;
        P.x = pk_pos(rn0.x, rn0.y); P.y = pk_pos(rn0.z, rn0.w);
        P.z = pk_pos(rn1.x, rn1.y); P.w = pk_pos(rn1.z, rn1.w);
        Q.x = pk_neg(rn0.x, rn0.y); Q.y = pk_neg(rn0.z, rn0.w);
        Q.z = pk_neg(rn1.x, rn1.y); Q.w = pk_neg(rn1.z, rn1.w);
        *(uint4*)(wb2 + wOff) = P;
        *(uint4*)(wb2 + 8192 + wOff) = Q;
      }
      __syncthreads();
      if (kt < 47) {
        const size_t ko = (size_t)(kt + 1) * 32;
        rn0 = *(const float4*)(src + ko);
        rn1 = *(const float4*)(src + ko + 4);
      }
      const char* rb = smem + (kt & 1) * 16384;
      const uint16_t* gk = gB + kt * 32;
      const bf16x8 b1 = *(const bf16x8*)(gk);
      const bf16x8 b2 = *(const bf16x8*)(gk + GSZ);
#pragma unroll
      for (int mf = 0; mf < 8; ++mf) {
        const int rowR = mf * 16 + r15;
        const int aoff = rowR * 64 + ((gq ^ ((rowR >> 1) & 3)) * 16);
        const bf16x8 ap = *(const bf16x8*)(rb + aoff);
        const bf16x8 an = *(const bf16x8*)(rb + 8192 + aoff);
        acc[mf] = MFMA(ap, b1, acc[mf], 0, 0, 0);
        acc[mf] = MFMA(an, b2, acc[mf], 0, 0, 0);
      }
    }
    const int col = w * 16 + r15;
#pragma unroll
    for (int mf = 0; mf < 8; ++mf) {
      const f32x4 nv = acc[mf];
#pragma unroll
      for (int q = 0; q < 4; ++q) {
        const size_t idx = (size_t)(row0 + mf * 16 + gq * 4 + q) * 128 + col;
        unsafeAtomicAdd(&node_part[idx], nv[q]);
      }
    }
  } else {
    for (int kt = 0; kt < 48; ++kt) {
      char* wb2 = smem + (kt & 1) * 16384;
      {
        uint4 E;
        E.x = pk_bf(rn0.x, rn0.y); E.y = pk_bf(rn0.z, rn0.w);
        E.z = pk_bf(rn1.x, rn1.y); E.w = pk_bf(rn1.z, rn1.w);
        *(uint4*)(wb2 + wOff) = E;
      }
      __syncthreads();
      if (kt < 47) {
        const size_t ko = (size_t)(kt + 1) * 32;
        rn0 = *(const float4*)(src + ko);
        rn1 = *(const float4*)(src + ko + 4);
      }
      const char* rb = smem + (kt & 1) * 16384;
      const bf16x8 b3 = *(const bf16x8*)(gB + kt * 32 + 2 * (size_t)GSZ);
#pragma unroll
      for (int mf = 0; mf < 8; ++mf) {
        const int rowR = mf * 16 + r15;
        const int aoff = rowR * 64 + ((gq ^ ((rowR >> 1) & 3)) * 16);
        const bf16x8 ae = *(const bf16x8*)(rb + aoff);
        acc[mf] = MFMA(ae, b3, acc[mf], 0, 0, 0);
      }
    }
    const int col = w * 16 + r15;
#pragma unroll
    for (int mf = 0; mf < 8; ++mf) {
      const f32x4 ev = acc[mf];
#pragma unroll
      for (int q = 0; q < 4; ++q) {
        const size_t idx = (size_t)(row0 + mf * 16 + gq * 4 + q) * 128 + col;
        unsafeAtomicAdd(&edge_part[idx], ev[q]);
      }
    }
  }
}

// ---------------------------------------------------------------------------
// Kernel 3: out = relu(node_part + node_bias) + edge_part + edge_bias
// ---------------------------------------------------------------------------
__global__ __launch_bounds__(256) void fgc_final(
    const float* __restrict__ node_part, const float* __restrict__ edge_part,
    const float* __restrict__ node_bias, const float* __restrict__ edge_bias,
    float* __restrict__ out) {
  const int idx = blockIdx.x * 256 + threadIdx.x;  // one float4 each
  const int col = (idx * 4) & 127;
  const float4 n = ((const float4*)node_part)[idx];
  const float4 e = ((const float4*)edge_part)[idx];
  const float4 nb = *(const float4*)(node_bias + col);
  const float4 eb = *(const float4*)(edge_bias + col);
  float4 o;
  o.x = fmaxf(n.x + nb.x, 0.f) + e.x + eb.x;
  o.y = fmaxf(n.y + nb.y, 0.f) + e.y + eb.y;
  o.z = fmaxf(n.z + nb.z, 0.f) + e.z + eb.z;
  o.w = fmaxf(n.w + nb.w, 0.f) + e.w + eb.w;
  ((float4*)out)[idx] = o;
}

extern "C" void kernel_launch(void* const* d_in, const int* in_sizes, int n_in,
                              void* d_out, int out_size, void* d_ws, size_t ws_size,
                              hipStream_t stream) {
  const float* feats = (const float*)d_in[0];
  const float* node_adj = (const float*)d_in[1];
  const float* edge_adj = (const float*)d_in[2];
  const float* node_w = (const float*)d_in[3];
  const float* node_b = (const float*)d_in[4];
  const float* edge_w = (const float*)d_in[5];
  const float* edge_b = (const float*)d_in[6];
  uint16_t* gt = (uint16_t*)d_ws;                 // 9.44 MB
  float* node_part = (float*)d_ws + NPART_OFF;    // 6.29 MB
  float* edge_part = (float*)d_ws + EPART_OFF;    // 6.29 MB

  gw_kernel<<<768, 256, 0, stream>>>(feats, node_w, edge_w, gt);
  hipMemsetAsync((char*)d_ws + 9437184, 0, 2 * 6291456, stream);
  fgc_main<<<1536, 512, 0, stream>>>(node_adj, edge_adj, gt,
                                     node_part, edge_part);
  fgc_final<<<1536, 256, 0, stream>>>(node_part, edge_part, node_b, edge_b,
                                      (float*)d_out);
}